// Round 5
// baseline (551.544 us; speedup 1.0000x reference)
//
#include <hip/hip_runtime.h>

#define NN 100000
#define NE 1600000
#define NG 4096
#define HID 128
#define ODIM 64
#define BN_EPS 1e-5f
#define NBUK 782    // ceil(NN/128) buckets of 128 nodes
#define BPAD 896    // max padding per bucket (128 nodes * 7)
#define NZROW 256   // distinct zero rows for dummy gathers (avoid hot-line)
#define CHUNK 16384 // edges per scatter block
#define PREP_HIST 256
#define PREP_GOFF 17  // ceil((NG+1)/256)
#define PREP_W 192    // 3 * 128*128 / 256

typedef unsigned int u32;
typedef unsigned short u16;
typedef short short8 __attribute__((ext_vector_type(8)));
typedef float f32x4 __attribute__((ext_vector_type(4)));

// bf16 pack (RNE) of two floats -> uint (lo = a, hi = b)
__device__ inline u32 pack_bf16(float a, float b) {
  u32 ua = __float_as_uint(a), ub = __float_as_uint(b);
  ua += 0x7fffu + ((ua >> 16) & 1u);
  ub += 0x7fffu + ((ub >> 16) & 1u);
  return (ua >> 16) | (ub & 0xffff0000u);
}
__device__ inline u16 bf16_of(float v) {
  u32 ua = __float_as_uint(v);
  ua += 0x7fffu + ((ua >> 16) & 1u);
  return (u16)(ua >> 16);
}
__device__ inline float bf_lo(u32 u) { return __uint_as_float(u << 16); }
__device__ inline float bf_hi(u32 u) { return __uint_as_float(u & 0xffff0000u); }

// ---------------- fused prep: bucket histogram + graph offsets + 3x weight transpose ----------------
__global__ __launch_bounds__(256) void k_prep(const int* __restrict__ ei, int* __restrict__ bcnt,
                                              const int* __restrict__ batch, int* __restrict__ goff,
                                              const float* __restrict__ W1, const float* __restrict__ W2,
                                              const float* __restrict__ W3, u16* __restrict__ Wt1,
                                              u16* __restrict__ Wt2, u16* __restrict__ Wt3) {
  __shared__ int h[NBUK];
  int b = blockIdx.x, t = threadIdx.x;
  if (b < PREP_HIST) {
    for (int i = t; i < NBUK; i += 256) h[i] = 0;
    __syncthreads();
    const int stride = PREP_HIST * 256;
    for (int e = b * 256 + t; e < NE; e += stride)
      atomicAdd(&h[ei[NE + e] >> 7], 1);
    __syncthreads();
    for (int i = t; i < NBUK; i += 256)
      if (h[i]) atomicAdd(&bcnt[i], h[i]);
  } else if (b < PREP_HIST + PREP_GOFF) {
    int g = (b - PREP_HIST) * 256 + t;
    if (g <= NG) {
      int lo = 0, hi = NN;
      while (lo < hi) { int mid = (lo + hi) >> 1; if (batch[mid] < g) lo = mid + 1; else hi = mid; }
      goff[g] = lo;
    }
  } else {
    int idx = (b - PREP_HIST - PREP_GOFF) * 256 + t;  // 0..49151
    int mat = idx >> 14;
    int rem = idx & 16383;
    int n = rem >> 7, k = rem & 127;
    const float* W = (mat == 0) ? W1 : (mat == 1) ? W2 : W3;
    u16* Wt = (mat == 0) ? Wt1 : (mat == 1) ? Wt2 : Wt3;
    Wt[(n << 7) + k] = bf16_of(W[(k << 7) + n]);
  }
}

// ---------------- scan bucket counts -> bucket offsets + cursors ----------------
__global__ __launch_bounds__(1024) void k_bscan(const int* __restrict__ bcnt, int* __restrict__ bboff,
                                                int* __restrict__ bcur) {
  __shared__ int ls[1024];
  int t = threadIdx.x;
  ls[t] = (t < NBUK) ? bcnt[t] : 0;
  __syncthreads();
  for (int d = 1; d < 1024; d <<= 1) {
    int v = 0;
    if (t >= d) v = ls[t - d];
    __syncthreads();
    ls[t] += v;
    __syncthreads();
  }
  if (t < NBUK) {
    int ex = (t == 0) ? 0 : ls[t - 1];
    bboff[t] = ex;
    bcur[t] = ex;
  }
  if (t == 0) bboff[NBUK] = NE;
}

// ---------------- scatter edges into bucket-major buffer, LDS-aggregated atomics ----------------
__global__ __launch_bounds__(1024) void k_bscatter(const int* __restrict__ ei, int* __restrict__ bcur,
                                                   u32* __restrict__ ebuf) {
  __shared__ int cnt[NBUK], rnk[NBUK], base[NBUK];
  int t = threadIdx.x;
  int e0 = blockIdx.x * CHUNK;
  for (int i = t; i < NBUK; i += 1024) { cnt[i] = 0; rnk[i] = 0; }
  __syncthreads();
  for (int i = t; i < CHUNK; i += 1024) {
    int e = e0 + i;
    if (e < NE) atomicAdd(&cnt[ei[NE + e] >> 7], 1);
  }
  __syncthreads();
  for (int i = t; i < NBUK; i += 1024) {
    int c = cnt[i];
    base[i] = c ? atomicAdd(&bcur[i], c) : 0;
  }
  __syncthreads();
  for (int i = t; i < CHUNK; i += 1024) {
    int e = e0 + i;
    if (e < NE) {
      int s = ei[e], d = ei[NE + e];
      int b = d >> 7;
      int r = atomicAdd(&rnk[b], 1);
      ebuf[base[b] + r] = ((u32)(d & 127) << 17) | (u32)s;
    }
  }
}

// ---------------- per-bucket CSR build: pad-to-8 per node, explicit end array, spread dummies ----------------
// csrc stores BYTE offsets (src_row * 256) so the gather address is a single v_add.
__global__ __launch_bounds__(256) void k_csr(const u32* __restrict__ ebuf, const int* __restrict__ bboff,
                                             int* __restrict__ off, int* __restrict__ oend,
                                             float* __restrict__ dinv, u32* __restrict__ csrc) {
  __shared__ int cnt[128], scn[128], cur[128];
  int b = blockIdx.x, t = threadIdx.x;
  int n0 = b << 7;
  int ebeg = bboff[b], eend = bboff[b + 1];
  int pboff = ebeg + BPAD * b;  // padded bucket base in csrc
  if (t < 128) cnt[t] = 0;
  __syncthreads();
  for (int e = ebeg + t; e < eend; e += 256) atomicAdd(&cnt[ebuf[e] >> 17], 1);
  __syncthreads();
  int pc = 0;
  if (t < 128) { pc = (cnt[t] + 7) & ~7; scn[t] = pc; }
  __syncthreads();
  for (int d = 1; d < 128; d <<= 1) {
    int v = 0;
    if (t >= d && t < 128) v = scn[t - d];
    __syncthreads();
    if (t < 128) scn[t] += v;
    __syncthreads();
  }
  int nvalid = min(128, NN - n0);
  if (t < 128) {
    int ex = scn[t] - pc;  // exclusive padded offset
    cur[t] = ex;           // real-edge cursor
    if (t < nvalid) {
      off[n0 + t] = pboff + ex;
      oend[n0 + t] = pboff + scn[t];  // end = beg + padded count (never touches the bucket gap)
      dinv[n0 + t] = rsqrtf((float)cnt[t] + 1.0f);
    }
  }
  __syncthreads();
  // scatter real edges into padded layout (store row byte offset)
  for (int e = ebeg + t; e < eend; e += 256) {
    u32 p = ebuf[e];
    int d = p >> 17;
    int pos = pboff + atomicAdd(&cur[d], 1);
    csrc[pos] = (p & 0x1ffffu) << 8;
  }
  // per-node padding: dummy srcs spread over NZROW zero rows (disjoint positions; no sync needed)
  if (t < 128) {
    int ex = scn[t] - pc;
    for (int i = cnt[t]; i < pc; ++i)
      csrc[pboff + ex + i] = (u32)(NN + ((n0 + t + i) & (NZROW - 1))) << 8;
  }
}

// ---------------- MFMA GEMM (layer 1): register-direct, 1 barrier. h2[r] = dinv[r]*(A[r]@W) ----------------
// A fragments loaded straight from global fp32 (16 rows x 128B per wave per k-step, full line use);
// B fragments straight from the 32KB L2-resident Wt. No LDS staging, no k-loop barriers.
__global__ __launch_bounds__(256) void k_gemm1(const float* __restrict__ A, const u16* __restrict__ Wt,
                                               const float* __restrict__ dinv, u16* __restrict__ H) {
  __shared__ u16 Ct[128][128];
  int t = threadIdx.x;
  int w = t >> 6, l = t & 63;
  int quad = l >> 4, lid = l & 15;
  int row0 = blockIdx.x * 128;

  f32x4 acc[2][8];
#pragma unroll
  for (int mt = 0; mt < 2; ++mt)
#pragma unroll
    for (int nt = 0; nt < 8; ++nt) acc[mt][nt] = (f32x4){0.f, 0.f, 0.f, 0.f};

  int ra0 = row0 + (w << 5) + lid;  // A row for fragment a0
  int ra1 = ra0 + 16;               // A row for fragment a1
  bool ok0 = ra0 < NN, ok1 = ra1 < NN;
  int cb = quad << 3;               // col base within the 32-wide k-slice

  for (int k0 = 0; k0 < HID; k0 += 32) {
    float4 f0 = {0, 0, 0, 0}, f1 = {0, 0, 0, 0}, f2 = {0, 0, 0, 0}, f3 = {0, 0, 0, 0};
    if (ok0) {
      const float4* ap = (const float4*)(A + (size_t)ra0 * HID + k0 + cb);
      f0 = ap[0]; f1 = ap[1];
    }
    if (ok1) {
      const float4* ap = (const float4*)(A + (size_t)ra1 * HID + k0 + cb);
      f2 = ap[0]; f3 = ap[1];
    }
    uint4 ua, ub;
    ua.x = pack_bf16(f0.x, f0.y); ua.y = pack_bf16(f0.z, f0.w);
    ua.z = pack_bf16(f1.x, f1.y); ua.w = pack_bf16(f1.z, f1.w);
    ub.x = pack_bf16(f2.x, f2.y); ub.y = pack_bf16(f2.z, f2.w);
    ub.z = pack_bf16(f3.x, f3.y); ub.w = pack_bf16(f3.z, f3.w);
    short8 a0, a1;
    *(uint4*)&a0 = ua;
    *(uint4*)&a1 = ub;
    const u16* wb = Wt + (size_t)lid * HID + k0 + cb;
#pragma unroll
    for (int nt = 0; nt < 8; ++nt) {
      short8 b = *(const short8*)(wb + (size_t)(nt << 4) * HID);
      acc[0][nt] = __builtin_amdgcn_mfma_f32_16x16x32_bf16(a0, b, acc[0][nt], 0, 0, 0);
      acc[1][nt] = __builtin_amdgcn_mfma_f32_16x16x32_bf16(a1, b, acc[1][nt], 0, 0, 0);
    }
  }

  int valid = min(128, NN - row0);
#pragma unroll
  for (int mt = 0; mt < 2; ++mt) {
#pragma unroll
    for (int r = 0; r < 4; ++r) {
      int rl = (w << 5) + (mt << 4) + (quad << 2) + r;
      float dv = (rl < valid) ? dinv[row0 + rl] : 0.f;
#pragma unroll
      for (int nt = 0; nt < 8; ++nt) {
        Ct[rl][(nt << 4) + lid] = bf16_of(acc[mt][nt][r] * dv);
      }
    }
  }
  __syncthreads();
  u16* Hb = H + (size_t)row0 * HID;
  int tot = valid << 4;
  for (int idx = t; idx < tot; idx += 256) {
    ((uint4*)Hb)[idx] = ((const uint4*)Ct)[idx];
  }
}

// BN+ReLU on a bf16 pair
__device__ inline u32 bn_pair(u32 v, float2 sc, float2 sh) {
  float a = fmaxf(fmaf(bf_lo(v), sc.x, sh.x), 0.f);
  float b = fmaxf(fmaf(bf_hi(v), sc.y, sh.y), 0.f);
  return pack_bf16(a, b);
}

// ---------------- MFMA GEMM (layers 2/3): register-direct, BN affine in registers, 2 barriers ----------------
__global__ __launch_bounds__(256) void k_gemm_b(const u16* __restrict__ A, const u16* __restrict__ Wt,
                                                const float* __restrict__ sums, const float* __restrict__ g,
                                                const float* __restrict__ be,
                                                const float* __restrict__ dinv, u16* __restrict__ H) {
  __shared__ u16 Ct[128][128];
  __shared__ float scsh[256];  // separate from Ct: no overlay hazard with the epilogue
  int t = threadIdx.x;
  int w = t >> 6, l = t & 63;
  int quad = l >> 4, lid = l & 15;
  int row0 = blockIdx.x * 128;

  if (t < 128) {  // inline bnfinal
    const float invN = 1.0f / (float)NN;
    float mu = sums[t] * invN;
    float var = sums[HID + t] * invN - mu * mu;
    float sc = g[t] * rsqrtf(var + BN_EPS);
    scsh[t] = sc;
    scsh[128 + t] = be[t] - mu * sc;
  }

  f32x4 acc[2][8];
#pragma unroll
  for (int mt = 0; mt < 2; ++mt)
#pragma unroll
    for (int nt = 0; nt < 8; ++nt) acc[mt][nt] = (f32x4){0.f, 0.f, 0.f, 0.f};

  int ra0 = row0 + (w << 5) + lid;
  int ra1 = ra0 + 16;
  bool ok0 = ra0 < NN, ok1 = ra1 < NN;
  int cb = quad << 3;
  __syncthreads();  // scsh visible

  for (int k0 = 0; k0 < HID; k0 += 32) {
    uint4 qa = {0, 0, 0, 0}, qb = {0, 0, 0, 0};
    if (ok0) qa = *(const uint4*)(A + (size_t)ra0 * HID + k0 + cb);
    if (ok1) qb = *(const uint4*)(A + (size_t)ra1 * HID + k0 + cb);
    const float2* scp = (const float2*)(scsh + k0 + cb);
    const float2* shp = (const float2*)(scsh + 128 + k0 + cb);
    float2 s0 = scp[0], s1 = scp[1], s2 = scp[2], s3 = scp[3];
    float2 h0 = shp[0], h1 = shp[1], h2 = shp[2], h3 = shp[3];
    qa.x = bn_pair(qa.x, s0, h0); qa.y = bn_pair(qa.y, s1, h1);
    qa.z = bn_pair(qa.z, s2, h2); qa.w = bn_pair(qa.w, s3, h3);
    qb.x = bn_pair(qb.x, s0, h0); qb.y = bn_pair(qb.y, s1, h1);
    qb.z = bn_pair(qb.z, s2, h2); qb.w = bn_pair(qb.w, s3, h3);
    short8 a0, a1;
    *(uint4*)&a0 = qa;
    *(uint4*)&a1 = qb;
    const u16* wb = Wt + (size_t)lid * HID + k0 + cb;
#pragma unroll
    for (int nt = 0; nt < 8; ++nt) {
      short8 b = *(const short8*)(wb + (size_t)(nt << 4) * HID);
      acc[0][nt] = __builtin_amdgcn_mfma_f32_16x16x32_bf16(a0, b, acc[0][nt], 0, 0, 0);
      acc[1][nt] = __builtin_amdgcn_mfma_f32_16x16x32_bf16(a1, b, acc[1][nt], 0, 0, 0);
    }
  }

  int valid = min(128, NN - row0);
#pragma unroll
  for (int mt = 0; mt < 2; ++mt) {
#pragma unroll
    for (int r = 0; r < 4; ++r) {
      int rl = (w << 5) + (mt << 4) + (quad << 2) + r;
      float dv = (rl < valid) ? dinv[row0 + rl] : 0.f;
#pragma unroll
      for (int nt = 0; nt < 8; ++nt) {
        Ct[rl][(nt << 4) + lid] = bf16_of(acc[mt][nt][r] * dv);
      }
    }
  }
  __syncthreads();
  u16* Hb = H + (size_t)row0 * HID;
  int tot = valid << 4;
  for (int idx = t; idx < tot; idx += 256) {
    ((uint4*)Hb)[idx] = ((const uint4*)Ct)[idx];
  }
}

// ---------------- pull aggregation: wave = node, half-wave pair-gather (dwordx2 = 2 rows/instr) ----------------
__global__ __launch_bounds__(256) void k_agg(const u16* __restrict__ h2, const int* __restrict__ off,
                                             const int* __restrict__ oend, const u32* __restrict__ csrc,
                                             const float* __restrict__ dinv, u16* __restrict__ aggb) {
  int node = (int)((blockIdx.x * 256 + threadIdx.x) >> 6);
  int lane = threadIdx.x & 63;
  if (node >= NN) return;
  int half = lane >> 5;                 // lanes 0-31: even edges, 32-63: odd edges
  u32 lb8 = (u32)(lane & 31) << 3;      // 8B per lane covers the 256B row with 32 lanes
  const char* h2b = (const char*)h2;
  int beg = off[node], end = oend[node];
  float f0 = 0.f, f1 = 0.f, f2 = 0.f, f3 = 0.f;
  if (half == 0) {  // self term once (halves are summed at the end)
    uint2 us = *(const uint2*)(h2b + (((size_t)node << 8) + lb8));
    f0 = bf_lo(us.x); f1 = bf_hi(us.x); f2 = bf_lo(us.y); f3 = bf_hi(us.y);
  }
  int e = beg;
  for (; e + 16 <= end; e += 16) {  // padded count is a multiple of 8
    u32 s[8]; uint2 v[8];
#pragma unroll
    for (int i = 0; i < 8; ++i) s[i] = csrc[e + 2 * i + half];
#pragma unroll
    for (int i = 0; i < 8; ++i) v[i] = *(const uint2*)(h2b + ((size_t)s[i] + lb8));
#pragma unroll
    for (int i = 0; i < 8; ++i) {
      f0 += bf_lo(v[i].x); f1 += bf_hi(v[i].x);
      f2 += bf_lo(v[i].y); f3 += bf_hi(v[i].y);
    }
  }
  if (e < end) {  // remainder is exactly 8 edges = 4 pairs
    u32 s[4]; uint2 v[4];
#pragma unroll
    for (int i = 0; i < 4; ++i) s[i] = csrc[e + 2 * i + half];
#pragma unroll
    for (int i = 0; i < 4; ++i) v[i] = *(const uint2*)(h2b + ((size_t)s[i] + lb8));
#pragma unroll
    for (int i = 0; i < 4; ++i) {
      f0 += bf_lo(v[i].x); f1 += bf_hi(v[i].x);
      f2 += bf_lo(v[i].y); f3 += bf_hi(v[i].y);
    }
  }
  // combine even/odd halves (same features live in lane L and lane L+32)
  f0 += __shfl_xor(f0, 32, 64);
  f1 += __shfl_xor(f1, 32, 64);
  f2 += __shfl_xor(f2, 32, 64);
  f3 += __shfl_xor(f3, 32, 64);
  if (half == 0) {
    float di = dinv[node];
    uint2 p;
    p.x = pack_bf16(f0 * di, f1 * di);
    p.y = pack_bf16(f2 * di, f3 * di);
    *(uint2*)((char*)aggb + (((size_t)node << 8) + lb8)) = p;
  }
}

// ---------------- BN statistics over bf16 agg (raw sums into buf) ----------------
__global__ __launch_bounds__(256) void k_bnstats(const u16* __restrict__ X, float* __restrict__ buf) {
  __shared__ float lsx[256], lssx[256], lsy[256], lssy[256];
  int t = threadIdx.x;
  int colp = t & 63, grp = t >> 6;
  int rbeg = blockIdx.x * 256, rend = min(rbeg + 256, NN);
  float sx = 0.f, ssx = 0.f, sy = 0.f, ssy = 0.f;
  for (int r = rbeg + grp; r < rend; r += 4) {
    u32 v = ((const u32*)(X + (size_t)r * HID))[colp];
    float a = bf_lo(v), b = bf_hi(v);
    sx += a; ssx = fmaf(a, a, ssx);
    sy += b; ssy = fmaf(b, b, ssy);
  }
  lsx[t] = sx; lssx[t] = ssx; lsy[t] = sy; lssy[t] = ssy;
  __syncthreads();
  if (t < 64) {
    sx = lsx[t] + lsx[t + 64] + lsx[t + 128] + lsx[t + 192];
    ssx = lssx[t] + lssx[t + 64] + lssx[t + 128] + lssx[t + 192];
    sy = lsy[t] + lsy[t + 64] + lsy[t + 128] + lsy[t + 192];
    ssy = lssy[t] + lssy[t + 64] + lssy[t + 128] + lssy[t + 192];
    atomicAdd(&buf[2 * colp], sx);
    atomicAdd(&buf[2 * colp + 1], sy);
    atomicAdd(&buf[HID + 2 * colp], ssx);
    atomicAdd(&buf[HID + 2 * colp + 1], ssy);
  }
}

// ---------------- fused mean-pool (inline BN+ReLU from raw sums) + FC ----------------
__global__ __launch_bounds__(256) void k_poolfc(const u16* __restrict__ aggb, const float* __restrict__ sums,
                                                const float* __restrict__ g3, const float* __restrict__ be3,
                                                const int* __restrict__ goff, const float* __restrict__ fcW,
                                                const float* __restrict__ fcb, float* __restrict__ out) {
  __shared__ float ls[4][128];
  int t = threadIdx.x;
  int w = t >> 6, lane = t & 63;
  int gr = blockIdx.x * 4 + w;  // grid = NG/4 exactly
  const float invN = 1.0f / (float)NN;
  int f0 = lane << 1, f1 = f0 + 1;
  float mu0 = sums[f0] * invN, mu1 = sums[f1] * invN;
  float v0 = sums[HID + f0] * invN - mu0 * mu0;
  float v1 = sums[HID + f1] * invN - mu1 * mu1;
  float sc0 = g3[f0] * rsqrtf(v0 + BN_EPS), sc1 = g3[f1] * rsqrtf(v1 + BN_EPS);
  float sh0 = be3[f0] - mu0 * sc0, sh1 = be3[f1] - mu1 * sc1;
  int beg = goff[gr], end = goff[gr + 1];
  float ax = 0.f, ay = 0.f;
  for (int r = beg; r < end; ++r) {
    u32 v = ((const u32*)(aggb + (size_t)r * HID))[lane];
    ax += fmaxf(fmaf(bf_lo(v), sc0, sh0), 0.f);
    ay += fmaxf(fmaf(bf_hi(v), sc1, sh1), 0.f);
  }
  float inv = 1.0f / fmaxf((float)(end - beg), 1.0f);
  ls[w][f0] = ax * inv;
  ls[w][f1] = ay * inv;
  __syncthreads();
  float acc = fcb[lane];
#pragma unroll 8
  for (int k = 0; k < HID; ++k) acc = fmaf(ls[w][k], fcW[(size_t)k * ODIM + lane], acc);
  out[(size_t)gr * ODIM + lane] = acc;
}

extern "C" void kernel_launch(void* const* d_in, const int* in_sizes, int n_in,
                              void* d_out, int out_size, void* d_ws, size_t ws_size,
                              hipStream_t stream) {
  const float* x     = (const float*)d_in[0];
  const int*   ei    = (const int*)d_in[1];
  const int*   batch = (const int*)d_in[2];
  const float* W1    = (const float*)d_in[3];
  // b1/b2/b3 (d_in[4,8,12]) skipped: per-feature bias cancels exactly in the following BN
  const float* g1    = (const float*)d_in[5];
  const float* be1   = (const float*)d_in[6];
  const float* W2    = (const float*)d_in[7];
  const float* g2    = (const float*)d_in[9];
  const float* be2   = (const float*)d_in[10];
  const float* W3    = (const float*)d_in[11];
  const float* g3    = (const float*)d_in[13];
  const float* be3   = (const float*)d_in[14];
  const float* fcW   = (const float*)d_in[15];
  const float* fcb   = (const float*)d_in[16];
  float* out = (float*)d_out;

  char* p = (char*)d_ws;
  auto alloc = [&](size_t bytes) { char* r = p; p += (bytes + 255) & ~(size_t)255; return r; };
  int*   bcnt   = (int*)alloc((size_t)NBUK * 4);
  float* bnb    = (float*)alloc(3 * 256 * 4);
  size_t zbytes = (size_t)(p - (char*)d_ws);
  int*   bboff  = (int*)alloc((size_t)(NBUK + 1) * 4);
  int*   bcur   = (int*)alloc((size_t)NBUK * 4);
  int*   off    = (int*)alloc((size_t)NN * 4);
  int*   oend   = (int*)alloc((size_t)NN * 4);
  float* dinv   = (float*)alloc((size_t)NN * 4);
  u32*   ebuf   = (u32*)alloc((size_t)NE * 4);
  u32*   csrc   = (u32*)alloc(((size_t)NE + (size_t)BPAD * NBUK) * 4);
  int*   goff   = (int*)alloc((size_t)(NG + 1) * 4);
  u16*   Wt1    = (u16*)alloc((size_t)HID * HID * 2);
  u16*   Wt2    = (u16*)alloc((size_t)HID * HID * 2);
  u16*   Wt3    = (u16*)alloc((size_t)HID * HID * 2);
  u16*   h2     = (u16*)alloc((size_t)(NN + NZROW) * HID * 2);  // + NZROW zero rows for dummies
  u16*   aggb   = (u16*)alloc((size_t)NN * HID * 2);

  hipMemsetAsync(d_ws, 0, zbytes, stream);
  hipMemsetAsync(h2 + (size_t)NN * HID, 0, (size_t)NZROW * HID * 2, stream);  // 64 KB zero rows

  const int NB = (NN + 255) / 256;          // 391
  const int GB = (NN + 127) / 128;          // 782 gemm blocks
  const int AGB = NN / 4;                   // 25000 agg blocks (4 waves = 4 nodes each)
  const int SB = (NE + CHUNK - 1) / CHUNK;  // 98 scatter blocks

  k_prep<<<PREP_HIST + PREP_GOFF + PREP_W, 256, 0, stream>>>(ei, bcnt, batch, goff, W1, W2, W3, Wt1, Wt2, Wt3);
  k_bscan<<<1, 1024, 0, stream>>>(bcnt, bboff, bcur);
  k_bscatter<<<SB, 1024, 0, stream>>>(ei, bcur, ebuf);
  k_csr<<<NBUK, 256, 0, stream>>>(ebuf, bboff, off, oend, dinv, csrc);

  // layer 1
  k_gemm1<<<GB, 256, 0, stream>>>(x, Wt1, dinv, h2);
  k_agg<<<AGB, 256, 0, stream>>>(h2, off, oend, csrc, dinv, aggb);
  k_bnstats<<<NB, 256, 0, stream>>>(aggb, bnb);
  // layer 2 (BN affine from layer-1 sums computed inline in gemm)
  k_gemm_b<<<GB, 256, 0, stream>>>(aggb, Wt2, bnb, g1, be1, dinv, h2);
  k_agg<<<AGB, 256, 0, stream>>>(h2, off, oend, csrc, dinv, aggb);
  k_bnstats<<<NB, 256, 0, stream>>>(aggb, bnb + 256);
  // layer 3
  k_gemm_b<<<GB, 256, 0, stream>>>(aggb, Wt3, bnb + 256, g2, be2, dinv, h2);
  k_agg<<<AGB, 256, 0, stream>>>(h2, off, oend, csrc, dinv, aggb);
  k_bnstats<<<NB, 256, 0, stream>>>(aggb, bnb + 512);
  // pool + BN + FC fused
  k_poolfc<<<NG / 4, 256, 0, stream>>>(aggb, bnb + 512, g3, be3, goff, fcW, fcb, out);
}

// Round 6
// 520.315 us; speedup vs baseline: 1.0600x; 1.0600x over previous
//
#include <hip/hip_runtime.h>

#define NN 100000
#define NE 1600000
#define NG 4096
#define HID 128
#define ODIM 64
#define BN_EPS 1e-5f
#define NBUK 782    // ceil(NN/128) buckets of 128 nodes
#define BPAD 896    // max padding per bucket (128 nodes * 7)
#define NZROW 256   // distinct zero rows for dummy gathers (avoid hot-line)
#define CHUNK 16384 // edges per scatter block
#define PREP_HIST 256
#define PREP_GOFF 17  // ceil((NG+1)/256)
#define PREP_W 192    // 3 * 128*128 / 256

typedef unsigned int u32;
typedef unsigned short u16;
typedef short short8 __attribute__((ext_vector_type(8)));
typedef float f32x4 __attribute__((ext_vector_type(4)));

// bf16 pack (RNE) of two floats -> uint (lo = a, hi = b)
__device__ inline u32 pack_bf16(float a, float b) {
  u32 ua = __float_as_uint(a), ub = __float_as_uint(b);
  ua += 0x7fffu + ((ua >> 16) & 1u);
  ub += 0x7fffu + ((ub >> 16) & 1u);
  return (ua >> 16) | (ub & 0xffff0000u);
}
__device__ inline u16 bf16_of(float v) {
  u32 ua = __float_as_uint(v);
  ua += 0x7fffu + ((ua >> 16) & 1u);
  return (u16)(ua >> 16);
}
__device__ inline float bf_lo(u32 u) { return __uint_as_float(u << 16); }
__device__ inline float bf_hi(u32 u) { return __uint_as_float(u & 0xffff0000u); }

// ---------------- fused prep: bucket histogram + graph offsets + 3x weight transpose ----------------
__global__ __launch_bounds__(256) void k_prep(const int* __restrict__ ei, int* __restrict__ bcnt,
                                              const int* __restrict__ batch, int* __restrict__ goff,
                                              const float* __restrict__ W1, const float* __restrict__ W2,
                                              const float* __restrict__ W3, u16* __restrict__ Wt1,
                                              u16* __restrict__ Wt2, u16* __restrict__ Wt3) {
  __shared__ int h[NBUK];
  int b = blockIdx.x, t = threadIdx.x;
  if (b < PREP_HIST) {
    for (int i = t; i < NBUK; i += 256) h[i] = 0;
    __syncthreads();
    const int stride = PREP_HIST * 256;
    for (int e = b * 256 + t; e < NE; e += stride)
      atomicAdd(&h[ei[NE + e] >> 7], 1);
    __syncthreads();
    for (int i = t; i < NBUK; i += 256)
      if (h[i]) atomicAdd(&bcnt[i], h[i]);
  } else if (b < PREP_HIST + PREP_GOFF) {
    int g = (b - PREP_HIST) * 256 + t;
    if (g <= NG) {
      int lo = 0, hi = NN;
      while (lo < hi) { int mid = (lo + hi) >> 1; if (batch[mid] < g) lo = mid + 1; else hi = mid; }
      goff[g] = lo;
    }
  } else {
    int idx = (b - PREP_HIST - PREP_GOFF) * 256 + t;  // 0..49151
    int mat = idx >> 14;
    int rem = idx & 16383;
    int n = rem >> 7, k = rem & 127;
    const float* W = (mat == 0) ? W1 : (mat == 1) ? W2 : W3;
    u16* Wt = (mat == 0) ? Wt1 : (mat == 1) ? Wt2 : Wt3;
    Wt[(n << 7) + k] = bf16_of(W[(k << 7) + n]);
  }
}

// ---------------- scan bucket counts -> bucket offsets + cursors ----------------
__global__ __launch_bounds__(1024) void k_bscan(const int* __restrict__ bcnt, int* __restrict__ bboff,
                                                int* __restrict__ bcur) {
  __shared__ int ls[1024];
  int t = threadIdx.x;
  ls[t] = (t < NBUK) ? bcnt[t] : 0;
  __syncthreads();
  for (int d = 1; d < 1024; d <<= 1) {
    int v = 0;
    if (t >= d) v = ls[t - d];
    __syncthreads();
    ls[t] += v;
    __syncthreads();
  }
  if (t < NBUK) {
    int ex = (t == 0) ? 0 : ls[t - 1];
    bboff[t] = ex;
    bcur[t] = ex;
  }
  if (t == 0) bboff[NBUK] = NE;
}

// ---------------- scatter edges into bucket-major buffer, LDS-aggregated atomics ----------------
__global__ __launch_bounds__(1024) void k_bscatter(const int* __restrict__ ei, int* __restrict__ bcur,
                                                   u32* __restrict__ ebuf) {
  __shared__ int cnt[NBUK], rnk[NBUK], base[NBUK];
  int t = threadIdx.x;
  int e0 = blockIdx.x * CHUNK;
  for (int i = t; i < NBUK; i += 1024) { cnt[i] = 0; rnk[i] = 0; }
  __syncthreads();
  for (int i = t; i < CHUNK; i += 1024) {
    int e = e0 + i;
    if (e < NE) atomicAdd(&cnt[ei[NE + e] >> 7], 1);
  }
  __syncthreads();
  for (int i = t; i < NBUK; i += 1024) {
    int c = cnt[i];
    base[i] = c ? atomicAdd(&bcur[i], c) : 0;
  }
  __syncthreads();
  for (int i = t; i < CHUNK; i += 1024) {
    int e = e0 + i;
    if (e < NE) {
      int s = ei[e], d = ei[NE + e];
      int b = d >> 7;
      int r = atomicAdd(&rnk[b], 1);
      ebuf[base[b] + r] = ((u32)(d & 127) << 17) | (u32)s;
    }
  }
}

// ---------------- per-bucket CSR build: pad-to-8 per node, explicit end array, spread dummies ----------------
// csrc stores BYTE offsets (src_row * 256) so the gather address is a single v_add.
__global__ __launch_bounds__(256) void k_csr(const u32* __restrict__ ebuf, const int* __restrict__ bboff,
                                             int* __restrict__ off, int* __restrict__ oend,
                                             float* __restrict__ dinv, u32* __restrict__ csrc) {
  __shared__ int cnt[128], scn[128], cur[128];
  int b = blockIdx.x, t = threadIdx.x;
  int n0 = b << 7;
  int ebeg = bboff[b], eend = bboff[b + 1];
  int pboff = ebeg + BPAD * b;  // padded bucket base in csrc
  if (t < 128) cnt[t] = 0;
  __syncthreads();
  for (int e = ebeg + t; e < eend; e += 256) atomicAdd(&cnt[ebuf[e] >> 17], 1);
  __syncthreads();
  int pc = 0;
  if (t < 128) { pc = (cnt[t] + 7) & ~7; scn[t] = pc; }
  __syncthreads();
  for (int d = 1; d < 128; d <<= 1) {
    int v = 0;
    if (t >= d && t < 128) v = scn[t - d];
    __syncthreads();
    if (t < 128) scn[t] += v;
    __syncthreads();
  }
  int nvalid = min(128, NN - n0);
  if (t < 128) {
    int ex = scn[t] - pc;  // exclusive padded offset
    cur[t] = ex;           // real-edge cursor
    if (t < nvalid) {
      off[n0 + t] = pboff + ex;
      oend[n0 + t] = pboff + scn[t];  // end = beg + padded count (never touches the bucket gap)
      dinv[n0 + t] = rsqrtf((float)cnt[t] + 1.0f);
    }
  }
  __syncthreads();
  // scatter real edges into padded layout (store row byte offset)
  for (int e = ebeg + t; e < eend; e += 256) {
    u32 p = ebuf[e];
    int d = p >> 17;
    int pos = pboff + atomicAdd(&cur[d], 1);
    csrc[pos] = (p & 0x1ffffu) << 8;
  }
  // per-node padding: dummy srcs spread over NZROW zero rows (disjoint positions; no sync needed)
  if (t < 128) {
    int ex = scn[t] - pc;
    for (int i = cnt[t]; i < pc; ++i)
      csrc[pboff + ex + i] = (u32)(NN + ((n0 + t + i) & (NZROW - 1))) << 8;
  }
}

// ---------------- MFMA GEMM (layer 1): A register-direct from global fp32, B staged once in LDS ----------------
// Zero barriers in the K-loop: A loads for step k+1 overlap MFMAs of step k.
// Bs layout per k-step is identical to the proven round-4 Bt fragment geometry: [kstep][n][32].
__global__ __launch_bounds__(256) void k_gemm1(const float* __restrict__ A, const u16* __restrict__ Wt,
                                               const float* __restrict__ dinv, u16* __restrict__ H) {
  __shared__ u16 Bs[4][128][32];               // 32 KB; aliased by Ct in the epilogue
  u16 (*Ct)[128] = (u16 (*)[128])&Bs[0][0][0];
  int t = threadIdx.x;
  int w = t >> 6, l = t & 63;
  int quad = l >> 4, lid = l & 15;
  int row0 = blockIdx.x * 128;

  // stage full B (128x128 bf16) into LDS: thread handles uint4 chunks
  {
    const uint4* src = (const uint4*)Wt;
#pragma unroll
    for (int rep = 0; rep < 8; ++rep) {
      int i = rep * 256 + t;       // 0..2047 uint4s
      int n = i >> 4, j = i & 15;  // j indexes 8-elem groups along k
      *(uint4*)&Bs[j >> 2][n][(j & 3) << 3] = src[i];
    }
  }

  f32x4 acc[2][8];
#pragma unroll
  for (int mt = 0; mt < 2; ++mt)
#pragma unroll
    for (int nt = 0; nt < 8; ++nt) acc[mt][nt] = (f32x4){0.f, 0.f, 0.f, 0.f};

  int ra0 = row0 + (w << 5) + lid;  // A row for fragment a0
  int ra1 = ra0 + 16;               // A row for fragment a1
  bool ok0 = ra0 < NN, ok1 = ra1 < NN;
  int cb = quad << 3;               // col base within the 32-wide k-slice
  __syncthreads();                  // Bs visible

#pragma unroll
  for (int ks = 0; ks < 4; ++ks) {
    int k0 = ks << 5;
    float4 f0 = {0, 0, 0, 0}, f1 = {0, 0, 0, 0}, f2 = {0, 0, 0, 0}, f3 = {0, 0, 0, 0};
    if (ok0) {
      const float4* ap = (const float4*)(A + (size_t)ra0 * HID + k0 + cb);
      f0 = ap[0]; f1 = ap[1];
    }
    if (ok1) {
      const float4* ap = (const float4*)(A + (size_t)ra1 * HID + k0 + cb);
      f2 = ap[0]; f3 = ap[1];
    }
    uint4 ua, ub;
    ua.x = pack_bf16(f0.x, f0.y); ua.y = pack_bf16(f0.z, f0.w);
    ua.z = pack_bf16(f1.x, f1.y); ua.w = pack_bf16(f1.z, f1.w);
    ub.x = pack_bf16(f2.x, f2.y); ub.y = pack_bf16(f2.z, f2.w);
    ub.z = pack_bf16(f3.x, f3.y); ub.w = pack_bf16(f3.z, f3.w);
    short8 a0, a1;
    *(uint4*)&a0 = ua;
    *(uint4*)&a1 = ub;
#pragma unroll
    for (int nt = 0; nt < 8; ++nt) {
      short8 b = *(const short8*)&Bs[ks][(nt << 4) + lid][cb];
      acc[0][nt] = __builtin_amdgcn_mfma_f32_16x16x32_bf16(a0, b, acc[0][nt], 0, 0, 0);
      acc[1][nt] = __builtin_amdgcn_mfma_f32_16x16x32_bf16(a1, b, acc[1][nt], 0, 0, 0);
    }
  }
  __syncthreads();  // all B reads done before Ct overwrites Bs

  int valid = min(128, NN - row0);
#pragma unroll
  for (int mt = 0; mt < 2; ++mt) {
#pragma unroll
    for (int r = 0; r < 4; ++r) {
      int rl = (w << 5) + (mt << 4) + (quad << 2) + r;
      float dv = (rl < valid) ? dinv[row0 + rl] : 0.f;
#pragma unroll
      for (int nt = 0; nt < 8; ++nt) {
        Ct[rl][(nt << 4) + lid] = bf16_of(acc[mt][nt][r] * dv);
      }
    }
  }
  __syncthreads();
  u16* Hb = H + (size_t)row0 * HID;
  int tot = valid << 4;
  for (int idx = t; idx < tot; idx += 256) {
    ((uint4*)Hb)[idx] = ((const uint4*)Ct)[idx];
  }
}

// BN+ReLU on a bf16 pair
__device__ inline u32 bn_pair(u32 v, float2 sc, float2 sh) {
  float a = fmaxf(fmaf(bf_lo(v), sc.x, sh.x), 0.f);
  float b = fmaxf(fmaf(bf_hi(v), sc.y, sh.y), 0.f);
  return pack_bf16(a, b);
}

// ---------------- MFMA GEMM (layers 2/3): A register-direct bf16 + in-register BN, B staged once in LDS ----------------
__global__ __launch_bounds__(256) void k_gemm_b(const u16* __restrict__ A, const u16* __restrict__ Wt,
                                                const float* __restrict__ sums, const float* __restrict__ g,
                                                const float* __restrict__ be,
                                                const float* __restrict__ dinv, u16* __restrict__ H) {
  __shared__ u16 Bs[4][128][32];               // 32 KB; aliased by Ct in the epilogue
  __shared__ float scsh[256];                  // separate: live during k-loop
  u16 (*Ct)[128] = (u16 (*)[128])&Bs[0][0][0];
  int t = threadIdx.x;
  int w = t >> 6, l = t & 63;
  int quad = l >> 4, lid = l & 15;
  int row0 = blockIdx.x * 128;

  if (t < 128) {  // inline bnfinal
    const float invN = 1.0f / (float)NN;
    float mu = sums[t] * invN;
    float var = sums[HID + t] * invN - mu * mu;
    float sc = g[t] * rsqrtf(var + BN_EPS);
    scsh[t] = sc;
    scsh[128 + t] = be[t] - mu * sc;
  }
  {
    const uint4* src = (const uint4*)Wt;
#pragma unroll
    for (int rep = 0; rep < 8; ++rep) {
      int i = rep * 256 + t;
      int n = i >> 4, j = i & 15;
      *(uint4*)&Bs[j >> 2][n][(j & 3) << 3] = src[i];
    }
  }

  f32x4 acc[2][8];
#pragma unroll
  for (int mt = 0; mt < 2; ++mt)
#pragma unroll
    for (int nt = 0; nt < 8; ++nt) acc[mt][nt] = (f32x4){0.f, 0.f, 0.f, 0.f};

  int ra0 = row0 + (w << 5) + lid;
  int ra1 = ra0 + 16;
  bool ok0 = ra0 < NN, ok1 = ra1 < NN;
  int cb = quad << 3;
  __syncthreads();  // Bs + scsh visible

#pragma unroll
  for (int ks = 0; ks < 4; ++ks) {
    int k0 = ks << 5;
    uint4 qa = {0, 0, 0, 0}, qb = {0, 0, 0, 0};
    if (ok0) qa = *(const uint4*)(A + (size_t)ra0 * HID + k0 + cb);
    if (ok1) qb = *(const uint4*)(A + (size_t)ra1 * HID + k0 + cb);
    const float2* scp = (const float2*)(scsh + k0 + cb);
    const float2* shp = (const float2*)(scsh + 128 + k0 + cb);
    float2 s0 = scp[0], s1 = scp[1], s2 = scp[2], s3 = scp[3];
    float2 h0 = shp[0], h1 = shp[1], h2 = shp[2], h3 = shp[3];
    qa.x = bn_pair(qa.x, s0, h0); qa.y = bn_pair(qa.y, s1, h1);
    qa.z = bn_pair(qa.z, s2, h2); qa.w = bn_pair(qa.w, s3, h3);
    qb.x = bn_pair(qb.x, s0, h0); qb.y = bn_pair(qb.y, s1, h1);
    qb.z = bn_pair(qb.z, s2, h2); qb.w = bn_pair(qb.w, s3, h3);
    short8 a0, a1;
    *(uint4*)&a0 = qa;
    *(uint4*)&a1 = qb;
#pragma unroll
    for (int nt = 0; nt < 8; ++nt) {
      short8 b = *(const short8*)&Bs[ks][(nt << 4) + lid][cb];
      acc[0][nt] = __builtin_amdgcn_mfma_f32_16x16x32_bf16(a0, b, acc[0][nt], 0, 0, 0);
      acc[1][nt] = __builtin_amdgcn_mfma_f32_16x16x32_bf16(a1, b, acc[1][nt], 0, 0, 0);
    }
  }
  __syncthreads();  // all B reads done before Ct overwrites Bs

  int valid = min(128, NN - row0);
#pragma unroll
  for (int mt = 0; mt < 2; ++mt) {
#pragma unroll
    for (int r = 0; r < 4; ++r) {
      int rl = (w << 5) + (mt << 4) + (quad << 2) + r;
      float dv = (rl < valid) ? dinv[row0 + rl] : 0.f;
#pragma unroll
      for (int nt = 0; nt < 8; ++nt) {
        Ct[rl][(nt << 4) + lid] = bf16_of(acc[mt][nt][r] * dv);
      }
    }
  }
  __syncthreads();
  u16* Hb = H + (size_t)row0 * HID;
  int tot = valid << 4;
  for (int idx = t; idx < tot; idx += 256) {
    ((uint4*)Hb)[idx] = ((const uint4*)Ct)[idx];
  }
}

// ---------------- pull aggregation: wave = node, half-wave pair-gather (dwordx2 = 2 rows/instr) ----------------
__global__ __launch_bounds__(256) void k_agg(const u16* __restrict__ h2, const int* __restrict__ off,
                                             const int* __restrict__ oend, const u32* __restrict__ csrc,
                                             const float* __restrict__ dinv, u16* __restrict__ aggb) {
  int node = (int)((blockIdx.x * 256 + threadIdx.x) >> 6);
  int lane = threadIdx.x & 63;
  if (node >= NN) return;
  int half = lane >> 5;                 // lanes 0-31: even edges, 32-63: odd edges
  u32 lb8 = (u32)(lane & 31) << 3;      // 8B per lane covers the 256B row with 32 lanes
  const char* h2b = (const char*)h2;
  int beg = off[node], end = oend[node];
  float f0 = 0.f, f1 = 0.f, f2 = 0.f, f3 = 0.f;
  if (half == 0) {  // self term once (halves are summed at the end)
    uint2 us = *(const uint2*)(h2b + (((size_t)node << 8) + lb8));
    f0 = bf_lo(us.x); f1 = bf_hi(us.x); f2 = bf_lo(us.y); f3 = bf_hi(us.y);
  }
  int e = beg;
  for (; e + 16 <= end; e += 16) {  // padded count is a multiple of 8
    u32 s[8]; uint2 v[8];
#pragma unroll
    for (int i = 0; i < 8; ++i) s[i] = csrc[e + 2 * i + half];
#pragma unroll
    for (int i = 0; i < 8; ++i) v[i] = *(const uint2*)(h2b + ((size_t)s[i] + lb8));
#pragma unroll
    for (int i = 0; i < 8; ++i) {
      f0 += bf_lo(v[i].x); f1 += bf_hi(v[i].x);
      f2 += bf_lo(v[i].y); f3 += bf_hi(v[i].y);
    }
  }
  if (e < end) {  // remainder is exactly 8 edges = 4 pairs
    u32 s[4]; uint2 v[4];
#pragma unroll
    for (int i = 0; i < 4; ++i) s[i] = csrc[e + 2 * i + half];
#pragma unroll
    for (int i = 0; i < 4; ++i) v[i] = *(const uint2*)(h2b + ((size_t)s[i] + lb8));
#pragma unroll
    for (int i = 0; i < 4; ++i) {
      f0 += bf_lo(v[i].x); f1 += bf_hi(v[i].x);
      f2 += bf_lo(v[i].y); f3 += bf_hi(v[i].y);
    }
  }
  // combine even/odd halves (same features live in lane L and lane L+32)
  f0 += __shfl_xor(f0, 32, 64);
  f1 += __shfl_xor(f1, 32, 64);
  f2 += __shfl_xor(f2, 32, 64);
  f3 += __shfl_xor(f3, 32, 64);
  if (half == 0) {
    float di = dinv[node];
    uint2 p;
    p.x = pack_bf16(f0 * di, f1 * di);
    p.y = pack_bf16(f2 * di, f3 * di);
    *(uint2*)((char*)aggb + (((size_t)node << 8) + lb8)) = p;
  }
}

// ---------------- BN statistics over bf16 agg (raw sums into buf) ----------------
__global__ __launch_bounds__(256) void k_bnstats(const u16* __restrict__ X, float* __restrict__ buf) {
  __shared__ float lsx[256], lssx[256], lsy[256], lssy[256];
  int t = threadIdx.x;
  int colp = t & 63, grp = t >> 6;
  int rbeg = blockIdx.x * 256, rend = min(rbeg + 256, NN);
  float sx = 0.f, ssx = 0.f, sy = 0.f, ssy = 0.f;
  for (int r = rbeg + grp; r < rend; r += 4) {
    u32 v = ((const u32*)(X + (size_t)r * HID))[colp];
    float a = bf_lo(v), b = bf_hi(v);
    sx += a; ssx = fmaf(a, a, ssx);
    sy += b; ssy = fmaf(b, b, ssy);
  }
  lsx[t] = sx; lssx[t] = ssx; lsy[t] = sy; lssy[t] = ssy;
  __syncthreads();
  if (t < 64) {
    sx = lsx[t] + lsx[t + 64] + lsx[t + 128] + lsx[t + 192];
    ssx = lssx[t] + lssx[t + 64] + lssx[t + 128] + lssx[t + 192];
    sy = lsy[t] + lsy[t + 64] + lsy[t + 128] + lsy[t + 192];
    ssy = lssy[t] + lssy[t + 64] + lssy[t + 128] + lssy[t + 192];
    atomicAdd(&buf[2 * colp], sx);
    atomicAdd(&buf[2 * colp + 1], sy);
    atomicAdd(&buf[HID + 2 * colp], ssx);
    atomicAdd(&buf[HID + 2 * colp + 1], ssy);
  }
}

// ---------------- fused mean-pool (inline BN+ReLU from raw sums) + FC ----------------
__global__ __launch_bounds__(256) void k_poolfc(const u16* __restrict__ aggb, const float* __restrict__ sums,
                                                const float* __restrict__ g3, const float* __restrict__ be3,
                                                const int* __restrict__ goff, const float* __restrict__ fcW,
                                                const float* __restrict__ fcb, float* __restrict__ out) {
  __shared__ float ls[4][128];
  int t = threadIdx.x;
  int w = t >> 6, lane = t & 63;
  int gr = blockIdx.x * 4 + w;  // grid = NG/4 exactly
  const float invN = 1.0f / (float)NN;
  int f0 = lane << 1, f1 = f0 + 1;
  float mu0 = sums[f0] * invN, mu1 = sums[f1] * invN;
  float v0 = sums[HID + f0] * invN - mu0 * mu0;
  float v1 = sums[HID + f1] * invN - mu1 * mu1;
  float sc0 = g3[f0] * rsqrtf(v0 + BN_EPS), sc1 = g3[f1] * rsqrtf(v1 + BN_EPS);
  float sh0 = be3[f0] - mu0 * sc0, sh1 = be3[f1] - mu1 * sc1;
  int beg = goff[gr], end = goff[gr + 1];
  float ax = 0.f, ay = 0.f;
  for (int r = beg; r < end; ++r) {
    u32 v = ((const u32*)(aggb + (size_t)r * HID))[lane];
    ax += fmaxf(fmaf(bf_lo(v), sc0, sh0), 0.f);
    ay += fmaxf(fmaf(bf_hi(v), sc1, sh1), 0.f);
  }
  float inv = 1.0f / fmaxf((float)(end - beg), 1.0f);
  ls[w][f0] = ax * inv;
  ls[w][f1] = ay * inv;
  __syncthreads();
  float acc = fcb[lane];
#pragma unroll 8
  for (int k = 0; k < HID; ++k) acc = fmaf(ls[w][k], fcW[(size_t)k * ODIM + lane], acc);
  out[(size_t)gr * ODIM + lane] = acc;
}

extern "C" void kernel_launch(void* const* d_in, const int* in_sizes, int n_in,
                              void* d_out, int out_size, void* d_ws, size_t ws_size,
                              hipStream_t stream) {
  const float* x     = (const float*)d_in[0];
  const int*   ei    = (const int*)d_in[1];
  const int*   batch = (const int*)d_in[2];
  const float* W1    = (const float*)d_in[3];
  // b1/b2/b3 (d_in[4,8,12]) skipped: per-feature bias cancels exactly in the following BN
  const float* g1    = (const float*)d_in[5];
  const float* be1   = (const float*)d_in[6];
  const float* W2    = (const float*)d_in[7];
  const float* g2    = (const float*)d_in[9];
  const float* be2   = (const float*)d_in[10];
  const float* W3    = (const float*)d_in[11];
  const float* g3    = (const float*)d_in[13];
  const float* be3   = (const float*)d_in[14];
  const float* fcW   = (const float*)d_in[15];
  const float* fcb   = (const float*)d_in[16];
  float* out = (float*)d_out;

  char* p = (char*)d_ws;
  auto alloc = [&](size_t bytes) { char* r = p; p += (bytes + 255) & ~(size_t)255; return r; };
  int*   bcnt   = (int*)alloc((size_t)NBUK * 4);
  float* bnb    = (float*)alloc(3 * 256 * 4);
  size_t zbytes = (size_t)(p - (char*)d_ws);
  int*   bboff  = (int*)alloc((size_t)(NBUK + 1) * 4);
  int*   bcur   = (int*)alloc((size_t)NBUK * 4);
  int*   off    = (int*)alloc((size_t)NN * 4);
  int*   oend   = (int*)alloc((size_t)NN * 4);
  float* dinv   = (float*)alloc((size_t)NN * 4);
  u32*   ebuf   = (u32*)alloc((size_t)NE * 4);
  u32*   csrc   = (u32*)alloc(((size_t)NE + (size_t)BPAD * NBUK) * 4);
  int*   goff   = (int*)alloc((size_t)(NG + 1) * 4);
  u16*   Wt1    = (u16*)alloc((size_t)HID * HID * 2);
  u16*   Wt2    = (u16*)alloc((size_t)HID * HID * 2);
  u16*   Wt3    = (u16*)alloc((size_t)HID * HID * 2);
  u16*   h2     = (u16*)alloc((size_t)(NN + NZROW) * HID * 2);  // + NZROW zero rows for dummies
  u16*   aggb   = (u16*)alloc((size_t)NN * HID * 2);

  hipMemsetAsync(d_ws, 0, zbytes, stream);
  hipMemsetAsync(h2 + (size_t)NN * HID, 0, (size_t)NZROW * HID * 2, stream);  // 64 KB zero rows

  const int NB = (NN + 255) / 256;          // 391
  const int GB = (NN + 127) / 128;          // 782 gemm blocks
  const int AGB = NN / 4;                   // 25000 agg blocks (4 waves = 4 nodes each)
  const int SB = (NE + CHUNK - 1) / CHUNK;  // 98 scatter blocks

  k_prep<<<PREP_HIST + PREP_GOFF + PREP_W, 256, 0, stream>>>(ei, bcnt, batch, goff, W1, W2, W3, Wt1, Wt2, Wt3);
  k_bscan<<<1, 1024, 0, stream>>>(bcnt, bboff, bcur);
  k_bscatter<<<SB, 1024, 0, stream>>>(ei, bcur, ebuf);
  k_csr<<<NBUK, 256, 0, stream>>>(ebuf, bboff, off, oend, dinv, csrc);

  // layer 1
  k_gemm1<<<GB, 256, 0, stream>>>(x, Wt1, dinv, h2);
  k_agg<<<AGB, 256, 0, stream>>>(h2, off, oend, csrc, dinv, aggb);
  k_bnstats<<<NB, 256, 0, stream>>>(aggb, bnb);
  // layer 2 (BN affine from layer-1 sums computed inline in gemm)
  k_gemm_b<<<GB, 256, 0, stream>>>(aggb, Wt2, bnb, g1, be1, dinv, h2);
  k_agg<<<AGB, 256, 0, stream>>>(h2, off, oend, csrc, dinv, aggb);
  k_bnstats<<<NB, 256, 0, stream>>>(aggb, bnb + 256);
  // layer 3
  k_gemm_b<<<GB, 256, 0, stream>>>(aggb, Wt3, bnb + 256, g2, be2, dinv, h2);
  k_agg<<<AGB, 256, 0, stream>>>(h2, off, oend, csrc, dinv, aggb);
  k_bnstats<<<NB, 256, 0, stream>>>(aggb, bnb + 512);
  // pool + BN + FC fused
  k_poolfc<<<NG / 4, 256, 0, stream>>>(aggb, bnb + 512, g3, be3, goff, fcW, fcb, out);
}